// Round 3
// baseline (157742.578 us; speedup 1.0000x reference)
//
#include <hip/hip_runtime.h>
#include <math.h>

#define NWG   65
#define DIM   256
#define LDM   260
#define TSTEPS 512
#define CLIPV 1.0e6f
#define TJIT  1.0e-4f
#define CJIT  1.0e-5f
#define MAXNLL 1.0e4f
#define LOG2PI 1.8378770664093453f

// scratch layout (float offsets into g_ws)
#define OFF_P    0
#define OFF_AP   66560
#define OFF_PP   133120
#define OFF_S    199680
#define OFF_L    266240
#define OFF_GT   332800   // 257 x 260
#define OFF_SY   399620
#define OFF_Q    466180
#define OFF_R    532740
#define OFF_VEC  599300   // mvec[256], predm[256], innov[256], gtz[256], rdiag[256], scal[...]

__device__ float    g_ws[600832];
__device__ unsigned g_bar[2];    // [0]=arrive count, [1]=generation (monotonic)
__device__ unsigned g_broken;    // latched if a barrier ever times out (diagnostic)

__device__ __forceinline__ void gbar() {
    __syncthreads();
    if (threadIdx.x == 0) {
        if (__hip_atomic_load(&g_broken, __ATOMIC_RELAXED, __HIP_MEMORY_SCOPE_AGENT) == 0u) {
            __threadfence();   // release this block's global writes
            unsigned g = __hip_atomic_load(&g_bar[1], __ATOMIC_SEQ_CST, __HIP_MEMORY_SCOPE_AGENT);
            unsigned a = __hip_atomic_fetch_add(&g_bar[0], 1u, __ATOMIC_SEQ_CST, __HIP_MEMORY_SCOPE_AGENT);
            if (a == (unsigned)(NWG - 1)) {
                __hip_atomic_store(&g_bar[0], 0u, __ATOMIC_SEQ_CST, __HIP_MEMORY_SCOPE_AGENT);
                __hip_atomic_fetch_add(&g_bar[1], 1u, __ATOMIC_SEQ_CST, __HIP_MEMORY_SCOPE_AGENT);
            } else {
                int spins = 0;
                while (__hip_atomic_load(&g_bar[1], __ATOMIC_SEQ_CST, __HIP_MEMORY_SCOPE_AGENT) == g) {
                    __builtin_amdgcn_s_sleep(2);
                    if (++spins > 2000000) {   // ~0.1 s: latch broken, free-run (diagnosable, no hang)
                        __hip_atomic_store(&g_broken, 1u, __ATOMIC_RELAXED, __HIP_MEMORY_SCOPE_AGENT);
                        break;
                    }
                }
            }
            __threadfence();   // acquire: subsequent loads see other blocks' writes
        }
    }
    __syncthreads();
}

__device__ __forceinline__ float fsan(float x) {
    x = isnan(x) ? 0.0f : x;
    return fminf(fmaxf(x, -CLIPV), CLIPV);
}
__device__ __forceinline__ float rdlane(float v, int l) {
    return __int_as_float(__builtin_amdgcn_readlane(__float_as_int(v), l));
}
__device__ __forceinline__ float wave_sum(float v) {
    #pragma unroll
    for (int off = 32; off; off >>= 1) v += __shfl_xor(v, off, 64);
    return v;
}

// one-wave 64x64 Cholesky of src (row stride sstride) -> Lm block at b0, rdiag = 1/L_ii.
// lane i holds row i in registers; symmetric-trailing invariant keeps
// column j readable from lane j's row (readlane broadcasts).
__device__ void chol64(const float* src, int sstride, float* Lm, float* rdiag, int b0) {
    const int lane = threadIdx.x & 63;
    float a[64];
    const float* srow = src + (size_t)lane * sstride;
    #pragma unroll
    for (int k = 0; k < 64; k += 4) {
        float4 v = *(const float4*)(srow + k);
        a[k] = v.x; a[k+1] = v.y; a[k+2] = v.z; a[k+3] = v.w;
    }
    float rdv = 0.0f;
    #pragma unroll
    for (int j = 0; j < 64; ++j) {
        float d  = rdlane(a[j], j);
        float sq = sqrtf(d);
        float rs = 1.0f / sq;
        if (lane == j) rdv = rs;
        if (lane >= j) a[j] *= rs;       // a[j] = l_ij
        float ljrs = a[j] * rs;          // l_ij / L_jj
        #pragma unroll
        for (int k = j + 1; k < 64; ++k) {
            float skj = rdlane(a[k], j); // trailing row j == (symmetry) column j at row k
            if (lane > j) a[k] = fmaf(-ljrs, skj, a[k]);
        }
    }
    float* lrow = Lm + (size_t)(b0 + lane) * LDM + b0;
    #pragma unroll
    for (int k = 0; k < 64; k += 4) {
        float4 v; v.x = a[k]; v.y = a[k+1]; v.z = a[k+2]; v.w = a[k+3];
        *(float4*)(lrow + k) = v;
    }
    rdiag[b0 + lane] = rdv;
}

// one wave solves L[b0 diag block] x = S[c, b0:b0+64]^T (row read by symmetry),
// writes x to L[c, b0:b0+64] (the trsm panel row of L).
__device__ void trsm_col_wave(const float* Sm, float* Lm, const float* rdiag, int b0, int c) {
    const int lane = threadIdx.x & 63;
    float b   = Sm[(size_t)c * LDM + b0 + lane];
    float rdl = rdiag[b0 + lane];
    float x   = 0.0f;
    const float* lbase = Lm + (size_t)(b0 + lane) * LDM + b0;
    for (int i0 = 0; i0 < 64; i0 += 4) {
        float4 lv = *(const float4*)(lbase + i0);
        #pragma unroll
        for (int s = 0; s < 4; ++s) {
            int i = i0 + s;
            float xi = rdlane(b, i) * rdlane(rdl, i);
            x = (lane == i) ? xi : x;
            float lvi = (s == 0) ? lv.x : (s == 1) ? lv.y : (s == 2) ? lv.z : lv.w;
            b = fmaf(-lvi, xi, b);   // lanes <= i corrupt their own (dead) b harmlessly
        }
    }
    Lm[(size_t)c * LDM + b0 + lane] = x;
}

// one wave: full 256 forward solve L y = rhs (rhs = PP column c, or innov for c==256);
// writes y to GT[c][0..255]
__device__ void gsolve_wave(const float* PPm, const float* innov, float* GT,
                            const float* Lm, const float* rdiag, int c) {
    const int lane = threadIdx.x & 63;
    float b[4], x[4], rd[4];
    const float* lp[4];
    #pragma unroll
    for (int q = 0; q < 4; ++q) {
        int r = lane + 64 * q;
        b[q]  = (c < 256) ? PPm[(size_t)c * LDM + r] : innov[r];
        x[q]  = 0.0f;
        rd[q] = rdiag[r];
        lp[q] = Lm + (size_t)r * LDM;
    }
    #pragma unroll
    for (int q = 0; q < 4; ++q) {             // pivot block (rows 64q..64q+63)
        for (int ii0 = 0; ii0 < 64; ii0 += 4) {
            float4 a0 = *(const float4*)(lp[0] + q * 64 + ii0);
            float4 a1 = *(const float4*)(lp[1] + q * 64 + ii0);
            float4 a2 = *(const float4*)(lp[2] + q * 64 + ii0);
            float4 a3 = *(const float4*)(lp[3] + q * 64 + ii0);
            #pragma unroll
            for (int s = 0; s < 4; ++s) {
                int il = ii0 + s;
                float xi = rdlane(b[q], il) * rdlane(rd[q], il);
                x[q] = (lane == il) ? xi : x[q];
                float c0 = (s==0)?a0.x:(s==1)?a0.y:(s==2)?a0.z:a0.w;
                float c1 = (s==0)?a1.x:(s==1)?a1.y:(s==2)?a1.z:a1.w;
                float c2 = (s==0)?a2.x:(s==1)?a2.y:(s==2)?a2.z:a2.w;
                float c3 = (s==0)?a3.x:(s==1)?a3.y:(s==2)?a3.z:a3.w;
                b[0] = fmaf(-c0, xi, b[0]);  // rows above pivot are dead values
                b[1] = fmaf(-c1, xi, b[1]);
                b[2] = fmaf(-c2, xi, b[2]);
                b[3] = fmaf(-c3, xi, b[3]);
            }
        }
    }
    #pragma unroll
    for (int q = 0; q < 4; ++q) GT[(size_t)c * LDM + lane + 64 * q] = x[q];
}

// WG-level: S[b1 diag block] -= Lpanel(b1 rows, col b0) * Lpanel^T (full 64x64)
__device__ void block_update64(float* Sm, const float* Lm, float* smem, int b1, int b0, int tid) {
    float* Ls = smem;   // [64][66]
    for (int e = tid; e < 64 * 64; e += 256) {
        int r = e >> 6, k = e & 63;
        Ls[r * 66 + k] = Lm[(size_t)(b1 + r) * LDM + b0 + k];
    }
    __syncthreads();
    int tx = tid & 15, ty = tid >> 4;
    int r0 = 4 * ty, c0 = 4 * tx;
    float acc[4][4] = {};
    for (int k = 0; k < 64; ++k) {
        float xr[4], yc[4];
        #pragma unroll
        for (int q = 0; q < 4; ++q) { xr[q] = Ls[(r0+q)*66 + k]; yc[q] = Ls[(c0+q)*66 + k]; }
        #pragma unroll
        for (int r = 0; r < 4; ++r)
            #pragma unroll
            for (int cc = 0; cc < 4; ++cc) acc[r][cc] = fmaf(xr[r], yc[cc], acc[r][cc]);
    }
    __syncthreads();
    #pragma unroll
    for (int r = 0; r < 4; ++r)
        #pragma unroll
        for (int cc = 0; cc < 4; ++cc)
            Sm[(size_t)(b1 + r0 + r) * LDM + b1 + c0 + cc] -= acc[r][cc];
}

// grid trailing update: S[rb:,rb:] -= Lp Lp^T over 32x32 tiles, skipping the
// next diagonal 64x64 block (handled by WG64), mirroring to keep S symmetric.
__device__ void trailing_tiles(float* Sm, const float* Lm, float* smem,
                               int rb, int nt, int b0, int wg, int tid) {
    int cnt = 0;
    for (int ti = 0; ti < nt; ++ti) {
        for (int tj = 0; tj <= ti; ++tj) {
            if (ti < 2 && tj < 2) continue;           // WG64's block
            if ((cnt++ & 63) != wg) continue;
            int i0 = rb + 32 * ti, j0 = rb + 32 * tj;
            float* Xs = smem;          // [32][66]
            float* Ys = smem + 32 * 66;
            for (int e = tid; e < 32 * 64; e += 256) {
                int r = e >> 6, k = e & 63;
                Xs[r * 66 + k] = Lm[(size_t)(i0 + r) * LDM + b0 + k];
                Ys[r * 66 + k] = Lm[(size_t)(j0 + r) * LDM + b0 + k];
            }
            __syncthreads();
            int tx = tid & 15, ty = tid >> 4;
            int r0 = 2 * ty, c0 = 2 * tx;
            float a00 = 0, a01 = 0, a10 = 0, a11 = 0;
            #pragma unroll 4
            for (int k = 0; k < 64; ++k) {
                float x0 = Xs[r0*66 + k], x1 = Xs[(r0+1)*66 + k];
                float y0 = Ys[c0*66 + k], y1 = Ys[(c0+1)*66 + k];
                a00 = fmaf(x0, y0, a00); a01 = fmaf(x0, y1, a01);
                a10 = fmaf(x1, y0, a10); a11 = fmaf(x1, y1, a11);
            }
            __syncthreads();
            int gi = i0 + r0, gj = j0 + c0;
            Sm[(size_t)gi * LDM + gj]           -= a00;
            Sm[(size_t)gi * LDM + gj + 1]       -= a01;
            Sm[(size_t)(gi + 1) * LDM + gj]     -= a10;
            Sm[(size_t)(gi + 1) * LDM + gj + 1] -= a11;
            if (ti != tj) {
                Sm[(size_t)gj * LDM + gi]           -= a00;
                Sm[(size_t)gj * LDM + gi + 1]       -= a10;
                Sm[(size_t)(gj + 1) * LDM + gi]     -= a01;
                Sm[(size_t)(gj + 1) * LDM + gi + 1] -= a11;
            }
        }
    }
}

__global__ __launch_bounds__(256, 1) void kf_kernel(
    const float* __restrict__ obs, const float* __restrict__ trans,
    const float* __restrict__ forc, const float* __restrict__ proc,
    const float* __restrict__ meas, const float* __restrict__ im,
    const float* __restrict__ icd, float* __restrict__ out)
{
    __shared__ float smem[4608];

    const int wg   = blockIdx.x;
    const int tid  = threadIdx.x;
    const int lane = tid & 63;
    const int wv   = tid >> 6;
    const int gw   = wg * 4 + wv;

    float* Pm  = g_ws + OFF_P;
    float* AP  = g_ws + OFF_AP;
    float* PPm = g_ws + OFF_PP;
    float* Sm  = g_ws + OFF_S;
    float* Lm  = g_ws + OFF_L;
    float* GT  = g_ws + OFF_GT;
    float* SY  = g_ws + OFF_SY;
    float* Qm  = g_ws + OFF_Q;
    float* Rm  = g_ws + OFF_R;
    float* vec = g_ws + OFF_VEC;
    float* mvec  = vec;
    float* predm = vec + 256;
    float* innov = vec + 512;
    float* gtz   = vec + 768;
    float* rdiag = vec + 1024;
    float* scal  = vec + 1280;   // [0]=zz, [1]=logdet, [2]=nll_sum

    float* out_filt = out + 1;
    float* out_pred = out + 1 + TSTEPS * DIM;

    // ---------------- pre-phase ----------------
    for (int e = wg * 256 + tid; e < DIM * DIM; e += NWG * 256) {
        int i = e >> 8, j = e & 255;
        float q = 0.5f * (fsan(proc[i * 256 + j]) + fsan(proc[j * 256 + i])) + (i == j ? TJIT : 0.0f);
        Qm[(size_t)i * LDM + j] = q;
        Rm[(size_t)i * LDM + j] = 0.5f * (fsan(meas[i * 256 + j]) + fsan(meas[j * 256 + i]));
        Pm[(size_t)i * LDM + j] = (i == j) ? fminf(fmaxf(icd[i], 1e-6f), CLIPV) : 0.0f;
    }
    if (wg == 64) {
        mvec[tid] = fsan(im[tid]);
        gtz[tid]  = 0.0f;
        if (tid < 3) scal[tid] = 0.0f;
    }
    gbar();

    for (int t = 0; t < TSTEPS; ++t) {
        const float* At = trans + (size_t)t * DIM * DIM;

        // ---- Ph1: AP = san(A) @ P   (WG64: finalize previous step) ----
        if (wg < 64) {
            int ti = wg >> 3, tj = wg & 7, i0 = ti * 32, j0 = tj * 32;
            int tx = tid & 15, ty = tid >> 4;
            int r0 = 2 * ty, c0 = 2 * tx;
            float a00 = 0, a01 = 0, a10 = 0, a11 = 0;
            float* As = smem;            // [32][66]
            float* Bs = smem + 32 * 66;  // [64][34]
            for (int kc = 0; kc < 256; kc += 64) {
                for (int e = tid; e < 32 * 64; e += 256) {
                    int r = e >> 6, k = e & 63;
                    As[r * 66 + k] = fsan(At[(i0 + r) * 256 + kc + k]);
                }
                for (int e = tid; e < 64 * 32; e += 256) {
                    int k = e >> 5, c = e & 31;
                    Bs[k * 34 + c] = Pm[(size_t)(kc + k) * LDM + j0 + c];
                }
                __syncthreads();
                #pragma unroll 8
                for (int k = 0; k < 64; ++k) {
                    float x0 = As[r0*66 + k], x1 = As[(r0+1)*66 + k];
                    float y0 = Bs[k*34 + c0], y1 = Bs[k*34 + c0 + 1];
                    a00 = fmaf(x0, y0, a00); a01 = fmaf(x0, y1, a01);
                    a10 = fmaf(x1, y0, a10); a11 = fmaf(x1, y1, a11);
                }
                __syncthreads();
            }
            AP[(size_t)(i0 + r0) * LDM + j0 + c0]         = a00;
            AP[(size_t)(i0 + r0) * LDM + j0 + c0 + 1]     = a01;
            AP[(size_t)(i0 + r0 + 1) * LDM + j0 + c0]     = a10;
            AP[(size_t)(i0 + r0 + 1) * LDM + j0 + c0 + 1] = a11;
        } else if (t > 0) {
            float nm = predm[tid] + gtz[tid];
            mvec[tid] = nm;
            out_filt[(size_t)(t - 1) * DIM + tid] = nm;
            if (tid == 0) {
                float nll = 0.5f * (scal[0] + scal[1] + 256.0f * LOG2PI);
                scal[2] += fminf(nll, MAXNLL);
            }
        }
        gbar();

        // ---- Ph2a: SY = AP @ san(A)^T ----
        if (wg < 64) {
            int ti = wg >> 3, tj = wg & 7, i0 = ti * 32, j0 = tj * 32;
            int tx = tid & 15, ty = tid >> 4;
            int r0 = 2 * ty, c0 = 2 * tx;
            float a00 = 0, a01 = 0, a10 = 0, a11 = 0;
            float* Xs = smem;
            float* Ys = smem + 32 * 66;
            for (int kc = 0; kc < 256; kc += 64) {
                for (int e = tid; e < 32 * 64; e += 256) {
                    int r = e >> 6, k = e & 63;
                    Xs[r * 66 + k] = AP[(size_t)(i0 + r) * LDM + kc + k];
                    Ys[r * 66 + k] = fsan(At[(j0 + r) * 256 + kc + k]);
                }
                __syncthreads();
                #pragma unroll 8
                for (int k = 0; k < 64; ++k) {
                    float x0 = Xs[r0*66 + k], x1 = Xs[(r0+1)*66 + k];
                    float y0 = Ys[c0*66 + k], y1 = Ys[(c0+1)*66 + k];
                    a00 = fmaf(x0, y0, a00); a01 = fmaf(x0, y1, a01);
                    a10 = fmaf(x1, y0, a10); a11 = fmaf(x1, y1, a11);
                }
                __syncthreads();
            }
            SY[(size_t)(i0 + r0) * LDM + j0 + c0]         = a00;
            SY[(size_t)(i0 + r0) * LDM + j0 + c0 + 1]     = a01;
            SY[(size_t)(i0 + r0 + 1) * LDM + j0 + c0]     = a10;
            SY[(size_t)(i0 + r0 + 1) * LDM + j0 + c0 + 1] = a11;
        }
        gbar();

        // ---- Ph2b: S = sym(SY)+Q+R+cI, PP = sym(SY)+Q ; pred_m, innov.
        //      WG64: build S(0,0) in LDS and run chol panel 0 (merged Ph3). ----
        if (gw < 256) {
            int r = gw;
            float s = 0.0f;
            #pragma unroll
            for (int q = 0; q < 4; ++q)
                s = fmaf(fsan(At[r * 256 + lane + 64 * q]), mvec[lane + 64 * q], s);
            s = wave_sum(s);
            if (lane == 0) {
                float pm = s + fsan(forc[(size_t)t * DIM + r]);
                predm[r] = pm;
                innov[r] = obs[(size_t)t * DIM + r] - pm;
                out_pred[(size_t)t * DIM + r] = pm;
            }
        }
        if (wg < 64) {
            for (int e = wg * 256 + tid; e < DIM * DIM; e += 64 * 256) {
                int i = e >> 8, j = e & 255;
                float sy = 0.5f * (SY[(size_t)i * LDM + j] + SY[(size_t)j * LDM + i]);
                float pp = sy + Qm[(size_t)i * LDM + j];
                PPm[(size_t)i * LDM + j] = pp;
                Sm[(size_t)i * LDM + j]  = pp + Rm[(size_t)i * LDM + j] + (i == j ? CJIT : 0.0f);
            }
        } else {
            float* Ss = smem;   // [64][68] (16B-aligned rows)
            for (int e = tid; e < 64 * 64; e += 256) {
                int i = e >> 6, j = e & 63;
                float sy = 0.5f * (SY[(size_t)i * LDM + j] + SY[(size_t)j * LDM + i]);
                Ss[i * 68 + j] = sy + Qm[(size_t)i * LDM + j] + Rm[(size_t)i * LDM + j]
                                 + (i == j ? CJIT : 0.0f);
            }
            __syncthreads();
            if (wv == 0) chol64(Ss, 68, Lm, rdiag, 0);
        }
        gbar();

        // ---- Ph4: trsm panel 0 (192 rows) ----
        if (gw < 192) trsm_col_wave(Sm, Lm, rdiag, 0, 64 + gw);
        gbar();

        // ---- Ph5: trailing(panel0) ; WG64: S11 update + chol panel 1 ----
        if (wg == 64) {
            block_update64(Sm, Lm, smem, 64, 0, tid);
            __syncthreads();
            if (wv == 0) chol64(Sm + (size_t)64 * LDM + 64, LDM, Lm, rdiag, 64);
        } else {
            trailing_tiles(Sm, Lm, smem, 64, 6, 0, wg, tid);
        }
        gbar();

        // ---- Ph6: trsm panel 1 (128 rows) ----
        if (gw < 128) trsm_col_wave(Sm, Lm, rdiag, 64, 128 + gw);
        gbar();

        // ---- Ph7: trailing(panel1) ; WG64: S22 update + chol panel 2 ----
        if (wg == 64) {
            block_update64(Sm, Lm, smem, 128, 64, tid);
            __syncthreads();
            if (wv == 0) chol64(Sm + (size_t)128 * LDM + 128, LDM, Lm, rdiag, 128);
        } else {
            trailing_tiles(Sm, Lm, smem, 128, 4, 64, wg, tid);
        }
        gbar();

        // ---- Ph8: trsm panel 2 (64 rows) ----
        if (gw < 64) trsm_col_wave(Sm, Lm, rdiag, 128, 192 + gw);
        gbar();

        // ---- Ph9: WG64: S33 update (panel2) + chol panel 3 ----
        if (wg == 64) {
            block_update64(Sm, Lm, smem, 192, 128, tid);
            __syncthreads();
            if (wv == 0) chol64(Sm + (size_t)192 * LDM + 192, LDM, Lm, rdiag, 192);
        }
        gbar();

        // ---- Ph10: G = L^{-1}[PP | innov]  (257 wave-parallel column solves) ----
        if (gw < 257) gsolve_wave(PPm, innov, GT, Lm, rdiag, gw);
        gbar();

        // ---- Ph11: newP = PP - G^T G ; gtz = G^T z ; zz ; logdet ----
        if (wg < 36) {
            int cnt = 0, ti = 0, tj = 0;
            for (int a = 0; a < 8; ++a)
                for (int b2 = 0; b2 <= a; ++b2) {
                    if (cnt == wg) { ti = a; tj = b2; }
                    ++cnt;
                }
            int i0 = ti * 32, j0 = tj * 32;
            int tx = tid & 15, ty = tid >> 4;
            int r0 = 2 * ty, c0 = 2 * tx;
            float a00 = 0, a01 = 0, a10 = 0, a11 = 0;
            float* Xs = smem;
            float* Ys = smem + 32 * 66;
            for (int kc = 0; kc < 256; kc += 64) {
                for (int e = tid; e < 32 * 64; e += 256) {
                    int r = e >> 6, k = e & 63;
                    Xs[r * 66 + k] = GT[(size_t)(i0 + r) * LDM + kc + k];
                    Ys[r * 66 + k] = GT[(size_t)(j0 + r) * LDM + kc + k];
                }
                __syncthreads();
                #pragma unroll 8
                for (int k = 0; k < 64; ++k) {
                    float x0 = Xs[r0*66 + k], x1 = Xs[(r0+1)*66 + k];
                    float y0 = Ys[c0*66 + k], y1 = Ys[(c0+1)*66 + k];
                    a00 = fmaf(x0, y0, a00); a01 = fmaf(x0, y1, a01);
                    a10 = fmaf(x1, y0, a10); a11 = fmaf(x1, y1, a11);
                }
                __syncthreads();
            }
            int gi = i0 + r0, gj = j0 + c0;
            float v00 = PPm[(size_t)gi * LDM + gj]           - a00;
            float v01 = PPm[(size_t)gi * LDM + gj + 1]       - a01;
            float v10 = PPm[(size_t)(gi + 1) * LDM + gj]     - a10;
            float v11 = PPm[(size_t)(gi + 1) * LDM + gj + 1] - a11;
            Pm[(size_t)gi * LDM + gj]           = v00;
            Pm[(size_t)gi * LDM + gj + 1]       = v01;
            Pm[(size_t)(gi + 1) * LDM + gj]     = v10;
            Pm[(size_t)(gi + 1) * LDM + gj + 1] = v11;
            if (ti != tj) {
                Pm[(size_t)gj * LDM + gi]           = v00;
                Pm[(size_t)gj * LDM + gi + 1]       = v10;
                Pm[(size_t)(gj + 1) * LDM + gi]     = v01;
                Pm[(size_t)(gj + 1) * LDM + gi + 1] = v11;
            }
        } else if (wg < 64) {
            // gtz rows: waves gw in [144, 256)
            for (int r = gw - 144; r < 256; r += 112) {
                float s = 0.0f;
                #pragma unroll
                for (int q = 0; q < 4; ++q)
                    s = fmaf(GT[(size_t)r * LDM + lane + 64 * q],
                             GT[(size_t)256 * LDM + lane + 64 * q], s);
                s = wave_sum(s);
                if (lane == 0) gtz[r] = s;
            }
        } else {
            if (wv == 0) {
                float s = 0.0f;
                #pragma unroll
                for (int q = 0; q < 4; ++q) {
                    float z = GT[(size_t)256 * LDM + lane + 64 * q];
                    s = fmaf(z, z, s);
                }
                s = wave_sum(s);
                if (lane == 0) scal[0] = s;
            } else if (wv == 1) {
                float s = 0.0f;
                #pragma unroll
                for (int q = 0; q < 4; ++q) s += logf(rdiag[lane + 64 * q]);
                s = wave_sum(s);
                if (lane == 0) scal[1] = -2.0f * s;   // logdet = 2*sum(log L_ii)
            }
        }
        gbar();
    }

    // ---------------- post: finalize t = 511 ----------------
    if (wg == 64) {
        float nm = predm[tid] + gtz[tid];
        out_filt[(size_t)511 * DIM + tid] = nm;
        if (tid == 0) {
            float nll = fminf(0.5f * (scal[0] + scal[1] + 256.0f * LOG2PI), MAXNLL);
            out[0] = scal[2] + nll;
            if (__hip_atomic_load(&g_broken, __ATOMIC_RELAXED, __HIP_MEMORY_SCOPE_AGENT) != 0u)
                out[0] = -1.2345678e7f;   // sentinel: barrier timed out
        }
    }
}

extern "C" void kernel_launch(void* const* d_in, const int* in_sizes, int n_in,
                              void* d_out, int out_size, void* d_ws, size_t ws_size,
                              hipStream_t stream) {
    (void)in_sizes; (void)n_in; (void)out_size; (void)d_ws; (void)ws_size;
    const float* obs  = (const float*)d_in[0];
    const float* trn  = (const float*)d_in[1];
    const float* forc = (const float*)d_in[2];
    const float* proc = (const float*)d_in[3];
    const float* meas = (const float*)d_in[4];
    const float* im   = (const float*)d_in[5];
    const float* icd  = (const float*)d_in[6];
    float* out = (float*)d_out;

    kf_kernel<<<dim3(NWG), dim3(256), 0, stream>>>(obs, trn, forc, proc, meas, im, icd, out);
}